// Round 16
// baseline (543.017 us; speedup 1.0000x reference)
//
#include <hip/hip_runtime.h>

#define NTOK 8192
#define CDIM 1024
#define ENUM 8
#define HDIM 4096

typedef unsigned short u16;
typedef unsigned int u32;
typedef __attribute__((ext_vector_type(8))) short s16x8;
typedef __attribute__((ext_vector_type(4))) float f32x4;
typedef __attribute__((ext_vector_type(16))) float f32x16;
typedef __attribute__((ext_vector_type(4))) u32 u32x4;
typedef __attribute__((ext_vector_type(2))) u32 u32x2;

static __device__ __forceinline__ u16 f2bf(float f) {
  union { float f; u32 u; } v; v.f = f;
  u32 r = v.u + 0x7fffu + ((v.u >> 16) & 1u);
  return (u16)(r >> 16);
}
static __device__ __forceinline__ u32 pack2(float a, float b) {
  return (u32)f2bf(a) | ((u32)f2bf(b) << 16);
}
static __device__ __forceinline__ float bflo(u32 v) {
  union { u32 u; float f; } x; x.u = v << 16; return x.f;
}
static __device__ __forceinline__ float bfhi(u32 v) {
  union { u32 u; float f; } x; x.u = v & 0xffff0000u; return x.f;
}

typedef __attribute__((address_space(1))) const void gvoid;
typedef __attribute__((address_space(3))) void lvoid;
static __device__ __forceinline__ void gload16(const u16* g, u16* l) {
  __builtin_amdgcn_global_load_lds((gvoid*)g, (lvoid*)l, 16, 0, 0);
}

static __device__ __forceinline__ float gelu_fast(float v) {
  float u = v * (1.5957691216f + 0.1426929792f * v * v);
  return v / (1.f + __expf(-u));
}

// ---------------- weight convert + transpose: w[E][K][N] f32 -> wt[E][N][K] bf16 ----
__global__ void wconv_kernel(const float* __restrict__ w, u16* __restrict__ wt,
                             int K, int N) {
  __shared__ float lt[64][65];
  const int e = blockIdx.z, k0 = blockIdx.y * 64, n0 = blockIdx.x * 64;
  const float* src = w + (size_t)e * K * N;
  u16* dst = wt + (size_t)e * N * K;
  const int t = threadIdx.x;
  const int tr = t >> 4, tc = (t & 15) * 4;
#pragma unroll
  for (int i = 0; i < 4; ++i) {
    f32x4 v = __builtin_nontemporal_load(
        (const f32x4*)(src + (size_t)(k0 + tr + i * 16) * N + n0 + tc));
    lt[tr + i * 16][tc] = v.x; lt[tr + i * 16][tc + 1] = v.y;
    lt[tr + i * 16][tc + 2] = v.z; lt[tr + i * 16][tc + 3] = v.w;
  }
  __syncthreads();
#pragma unroll
  for (int i = 0; i < 4; ++i) {
    int n = tr + i * 16;
    uint2 o;
    o.x = pack2(lt[tc + 0][n], lt[tc + 1][n]);
    o.y = pack2(lt[tc + 2][n], lt[tc + 3][n]);
    *(uint2*)(dst + (size_t)(n0 + n) * K + k0 + tc) = o;
  }
}

// ---------------- gating: 32 tokens/block, LDS-aggregated counts ----------------
__global__ void gate_kernel(const float* __restrict__ x, const float* __restrict__ wg,
                            int* __restrict__ cnt, int* __restrict__ tok_e,
                            float* __restrict__ tok_w) {
  __shared__ int lcnt[ENUM];
  const int tid = threadIdx.x;
  if (tid < ENUM) lcnt[tid] = 0;
  __syncthreads();
  const int wv = tid >> 6, lane = tid & 63;
  const int tbase = blockIdx.x * 32 + wv * 8;
  for (int t = 0; t < 8; ++t) {
    const int gw = tbase + t;
    const float* xr = x + (size_t)gw * CDIM;
    float acc[ENUM];
#pragma unroll
    for (int e = 0; e < ENUM; ++e) acc[e] = 0.f;
#pragma unroll 4
    for (int i = 0; i < CDIM / 64; ++i) {
      int c = i * 64 + lane;
      float xv = xr[c];
      float4 wa = *(const float4*)(wg + (size_t)c * ENUM);
      float4 wb = *(const float4*)(wg + (size_t)c * ENUM + 4);
      acc[0] += xv * wa.x; acc[1] += xv * wa.y; acc[2] += xv * wa.z; acc[3] += xv * wa.w;
      acc[4] += xv * wb.x; acc[5] += xv * wb.y; acc[6] += xv * wb.z; acc[7] += xv * wb.w;
    }
#pragma unroll
    for (int e = 0; e < ENUM; ++e) {
#pragma unroll
      for (int off = 32; off > 0; off >>= 1) acc[e] += __shfl_xor(acc[e], off);
    }
    if (lane == 0) {
      int i0 = 0; float v0 = acc[0];
#pragma unroll
      for (int e = 1; e < ENUM; ++e) if (acc[e] > v0) { v0 = acc[e]; i0 = e; }
      int i1 = -1; float v1 = -3.4e38f;
#pragma unroll
      for (int e = 0; e < ENUM; ++e) if (e != i0 && acc[e] > v1) { v1 = acc[e]; i1 = e; }
      float ex = expf(v1 - v0);
      float den = 1.f + ex;
      tok_e[gw * 2] = i0;     tok_w[gw * 2] = 1.f / den;
      tok_e[gw * 2 + 1] = i1; tok_w[gw * 2 + 1] = ex / den;
      atomicAdd(&lcnt[i0], 1); atomicAdd(&lcnt[i1], 1);
    }
  }
  __syncthreads();
  if (tid < ENUM) {
    int v = lcnt[tid];
    if (v) atomicAdd(&cnt[tid], v);
  }
}

__global__ void offsets_kernel(const int* __restrict__ cnt, int* __restrict__ offs) {
  if (threadIdx.x == 0 && blockIdx.x == 0) {
    int s = 0;
    for (int e = 0; e < ENUM; ++e) { offs[e] = s; s += cnt[e]; }
  }
}

// ---------------- assign: LDS-aggregated ranks, 8 global atomics/block ----------
__global__ void assign_kernel(const int* __restrict__ tok_e, const int* __restrict__ offs,
                              int* __restrict__ fill, int* __restrict__ slot_tok,
                              int* __restrict__ tok_slot) {
  __shared__ int lfill[ENUM], lbase[ENUM];
  const int tid = threadIdx.x;
  if (tid < ENUM) lfill[tid] = 0;
  __syncthreads();
  const int n = blockIdx.x * 256 + tid;
  const int e0 = tok_e[n * 2], e1 = tok_e[n * 2 + 1];
  const int p0 = atomicAdd(&lfill[e0], 1);
  const int p1 = atomicAdd(&lfill[e1], 1);
  __syncthreads();
  if (tid < ENUM) lbase[tid] = lfill[tid] ? atomicAdd(&fill[tid], lfill[tid]) : 0;
  __syncthreads();
  const int s0 = offs[e0] + lbase[e0] + p0;
  const int s1 = offs[e1] + lbase[e1] + p1;
  slot_tok[s0] = n; tok_slot[n * 2] = s0;
  slot_tok[s1] = n; tok_slot[n * 2 + 1] = s1;
}

__global__ void gather_kernel(const float* __restrict__ x, const int* __restrict__ slot_tok,
                              u16* __restrict__ xg) {
  int gid = blockIdx.x * blockDim.x + threadIdx.x;
  int slot = gid >> 8;
  int c4 = (gid & 255) * 4;
  int tok = slot_tok[slot];
  float4 v = *(const float4*)(x + (size_t)tok * CDIM + c4);
  uint2 o; o.x = pack2(v.x, v.y); o.y = pack2(v.z, v.w);
  *(uint2*)(xg + (size_t)slot * CDIM + c4) = o;
}

// ---------------- expert GEMMs (R11 body, 32x32x16 MFMA) ----------------
// 128x128, BK=64, 4 waves, gload_lds + both-sides XOR swizzle, XCD-chunked.
// Per wave: 2x2 of 32x32 tiles, K-steps of 16; 16 ds_read_b128 + 16 MFMA / K-tile
// (vs 32 MFMA of 16x16x32: -17% matrix-pipe issue cycles, same LDS traffic,
// same 64-AGPR acc -> same occupancy class).
// C/D layout [m74/m101]: col=lane&31, row=(reg&3)+8*(reg>>2)+4*(lane>>5).
template <int PHASE>
__global__ __launch_bounds__(256, 2) void moe_gemm(
    const u16* __restrict__ Ag, const u16* __restrict__ Bt, const float* __restrict__ bias,
    u16* __restrict__ outp,
    const int* __restrict__ cnts, const int* __restrict__ offs,
    int K, int Nn) {
  const int e = blockIdx.z;
  const int cnt = cnts[e];
  const int NT = gridDim.x;
  const int MTC = gridDim.y >> 3;               // 8
  const int r = blockIdx.y * NT + blockIdx.x;   // launch-order flat (x fastest)
  const int k = r & 7;                          // XCD id
  const int i = r >> 3;                         // inner
  const int ck = (k + e) & 7;                   // rotated chunk for balance
  const int mt = ck * MTC + (i % MTC);
  const int nt = i / MTC;
  if (mt * 128 >= cnt) return;
  const int moff = offs[e];
  const int tid = threadIdx.x;
  const int wv = tid >> 6, ln = tid & 63;
  const int l31 = ln & 31, lh = ln >> 5;
  const int wm = wv >> 1, wn = wv & 1;

  __shared__ __align__(16) u16 lds[2][128 * 64];
  u16* lA = lds[0];
  u16* lB = lds[1];

  const u16* Abase = Ag + (size_t)moff * K;
  const u16* Bbase = Bt + (size_t)e * Nn * K + (size_t)nt * 128 * K;

  const int srow = ln >> 3;                       // row-in-chunk 0..7
  const int sk = (((ln & 7) ^ srow)) * 8;         // swizzled source octet offset

  f32x16 acc[2][2];
#pragma unroll
  for (int mi = 0; mi < 2; ++mi)
#pragma unroll
    for (int ni = 0; ni < 2; ++ni)
#pragma unroll
      for (int q = 0; q < 16; ++q) acc[mi][ni][q] = 0.f;

  const int nk = K / 64;
  for (int kt = 0; kt < nk; ++kt) {
#pragma unroll
    for (int i4 = 0; i4 < 4; ++i4) {
      int c = wv * 4 + i4;
      int ra = mt * 128 + c * 8 + srow;
      ra = ra < cnt ? ra : cnt - 1;  // clamp: padded rows discarded in epilogue
      gload16(Abase + (size_t)ra * K + kt * 64 + sk, lA + c * 512);
      gload16(Bbase + (size_t)(c * 8 + srow) * K + kt * 64 + sk, lB + c * 512);
    }
    __syncthreads();
#pragma unroll
    for (int ks = 0; ks < 4; ++ks) {   // 4 K-steps of 16
      const int po = ((ks * 2 + lh) ^ (l31 & 7)) * 8;  // swizzled octet (rows ≡ l31 mod 8)
      s16x8 af[2], bfr[2];
#pragma unroll
      for (int mi = 0; mi < 2; ++mi)
        af[mi] = *(const s16x8*)(lA + (wm * 64 + mi * 32 + l31) * 64 + po);
#pragma unroll
      for (int ni = 0; ni < 2; ++ni)
        bfr[ni] = *(const s16x8*)(lB + (wn * 64 + ni * 32 + l31) * 64 + po);
#pragma unroll
      for (int mi = 0; mi < 2; ++mi)
#pragma unroll
        for (int ni = 0; ni < 2; ++ni)
          acc[mi][ni] =
              __builtin_amdgcn_mfma_f32_32x32x16_bf16(af[mi], bfr[ni], acc[mi][ni], 0, 0, 0);
    }
    __syncthreads();
  }

  // epilogue: bias (+gelu), pack bf16 into LDS tile [128][128], coalesced store
  u16* lT = lds[0];
  float bv2[2];
#pragma unroll
  for (int ni = 0; ni < 2; ++ni)
    bv2[ni] = bias[(size_t)e * Nn + nt * 128 + wn * 64 + ni * 32 + l31];
#pragma unroll
  for (int mi = 0; mi < 2; ++mi) {
#pragma unroll
    for (int ni = 0; ni < 2; ++ni) {
#pragma unroll
      for (int q = 0; q < 16; ++q) {
        int row = wm * 64 + mi * 32 + (q & 3) + 8 * (q >> 2) + 4 * lh;
        int col = wn * 64 + ni * 32 + l31;
        float v = acc[mi][ni][q] + bv2[ni];
        if (PHASE == 1) v = gelu_fast(v);
        lT[row * 128 + col] = f2bf(v);
      }
    }
  }
  __syncthreads();
#pragma unroll
  for (int j = 0; j < 8; ++j) {
    int u = j * 256 + tid;           // u32x4 index into 128x128 tile
    int row = u >> 4;                // 16 u32x4 per row
    int colb = (u & 15) * 8;
    int grow = mt * 128 + row;
    if (grow < cnt) {
      u32x4 v = ((const u32x4*)lT)[u];
      *(u32x4*)(outp + (size_t)(moff + grow) * Nn + nt * 128 + colb) = v;
    }
  }
}

// out[tok] = w0 * y[slot0] + w1 * y[slot1]   (y read-once -> NT loads)
__global__ void combine_kernel(const u16* __restrict__ y, const int* __restrict__ tok_slot,
                               const float* __restrict__ tok_w, float* __restrict__ out) {
  int gid = blockIdx.x * blockDim.x + threadIdx.x;
  int n = gid >> 8;
  int c4 = (gid & 255) * 4;
  int s0 = tok_slot[n * 2], s1 = tok_slot[n * 2 + 1];
  float w0 = tok_w[n * 2], w1 = tok_w[n * 2 + 1];
  u32x2 a = __builtin_nontemporal_load((const u32x2*)(y + (size_t)s0 * CDIM + c4));
  u32x2 b = __builtin_nontemporal_load((const u32x2*)(y + (size_t)s1 * CDIM + c4));
  float4 o;
  o.x = w0 * bflo(a.x) + w1 * bflo(b.x);
  o.y = w0 * bfhi(a.x) + w1 * bfhi(b.x);
  o.z = w0 * bflo(a.y) + w1 * bflo(b.y);
  o.w = w0 * bfhi(a.y) + w1 * bfhi(b.y);
  *(float4*)(out + (size_t)n * CDIM + c4) = o;
}

extern "C" void kernel_launch(void* const* d_in, const int* in_sizes, int n_in,
                              void* d_out, int out_size, void* d_ws, size_t ws_size,
                              hipStream_t stream) {
  const float* x  = (const float*)d_in[0];
  const float* wg = (const float*)d_in[1];
  const float* w1 = (const float*)d_in[2];
  const float* b1 = (const float*)d_in[3];
  const float* w2 = (const float*)d_in[4];
  const float* b2 = (const float*)d_in[5];
  float* out = (float*)d_out;

  char* ws = (char*)d_ws;
  int* cnt  = (int*)ws;
  int* fill = cnt + 8;
  int* offs = cnt + 16;
  size_t off = 256;
  int*   tok_e    = (int*)(ws + off);   off += (size_t)NTOK * 2 * 4;
  float* tok_w    = (float*)(ws + off); off += (size_t)NTOK * 2 * 4;
  int*   slot_tok = (int*)(ws + off);   off += (size_t)NTOK * 2 * 4;
  int*   tok_slot = (int*)(ws + off);   off += (size_t)NTOK * 2 * 4;
  u16*   xg  = (u16*)(ws + off); off += (size_t)NTOK * 2 * CDIM * 2;
  u16*   h   = (u16*)(ws + off); off += (size_t)NTOK * 2 * HDIM * 2;
  u16*   y   = (u16*)(ws + off); off += (size_t)NTOK * 2 * CDIM * 2;
  u16*   w1t = (u16*)(ws + off); off += (size_t)ENUM * CDIM * HDIM * 2;
  u16*   w2t = (u16*)(ws + off); off += (size_t)ENUM * HDIM * CDIM * 2;

  hipMemsetAsync(cnt, 0, 64, stream);

  wconv_kernel<<<dim3(HDIM / 64, CDIM / 64, ENUM), 256, 0, stream>>>(w1, w1t, CDIM, HDIM);
  wconv_kernel<<<dim3(CDIM / 64, HDIM / 64, ENUM), 256, 0, stream>>>(w2, w2t, HDIM, CDIM);

  gate_kernel<<<NTOK / 32, 256, 0, stream>>>(x, wg, cnt, tok_e, tok_w);
  offsets_kernel<<<1, 64, 0, stream>>>(cnt, offs);
  assign_kernel<<<NTOK / 256, 256, 0, stream>>>(tok_e, offs, fill, slot_tok, tok_slot);
  gather_kernel<<<NTOK * 2, 256, 0, stream>>>(x, slot_tok, xg);

  moe_gemm<1><<<dim3(HDIM / 128, NTOK / 128, ENUM), 256, 0, stream>>>(
      xg, w1t, b1, h, cnt, offs, CDIM, HDIM);
  moe_gemm<2><<<dim3(CDIM / 128, NTOK / 128, ENUM), 256, 0, stream>>>(
      h, w2t, b2, y, cnt, offs, HDIM, CDIM);

  combine_kernel<<<NTOK, 256, 0, stream>>>(y, tok_slot, tok_w, out);
}

// Round 17
// 507.742 us; speedup vs baseline: 1.0695x; 1.0695x over previous
//
#include <hip/hip_runtime.h>

#define NTOK 8192
#define CDIM 1024
#define ENUM 8
#define HDIM 4096

typedef unsigned short u16;
typedef unsigned int u32;
typedef __attribute__((ext_vector_type(8))) short s16x8;
typedef __attribute__((ext_vector_type(4))) float f32x4;
typedef __attribute__((ext_vector_type(4))) u32 u32x4;
typedef __attribute__((ext_vector_type(2))) u32 u32x2;

static __device__ __forceinline__ u16 f2bf(float f) {
  union { float f; u32 u; } v; v.f = f;
  u32 r = v.u + 0x7fffu + ((v.u >> 16) & 1u);
  return (u16)(r >> 16);
}
static __device__ __forceinline__ u32 pack2(float a, float b) {
  return (u32)f2bf(a) | ((u32)f2bf(b) << 16);
}
static __device__ __forceinline__ float bflo(u32 v) {
  union { u32 u; float f; } x; x.u = v << 16; return x.f;
}
static __device__ __forceinline__ float bfhi(u32 v) {
  union { u32 u; float f; } x; x.u = v & 0xffff0000u; return x.f;
}

typedef __attribute__((address_space(1))) const void gvoid;
typedef __attribute__((address_space(3))) void lvoid;
static __device__ __forceinline__ void gload16(const u16* g, u16* l) {
  __builtin_amdgcn_global_load_lds((gvoid*)g, (lvoid*)l, 16, 0, 0);
}

static __device__ __forceinline__ float gelu_fast(float v) {
  float u = v * (1.5957691216f + 0.1426929792f * v * v);
  return v / (1.f + __expf(-u));
}

// ---------------- weight convert + transpose: w[E][K][N] f32 -> wt[E][N][K] bf16 ----
__global__ void wconv_kernel(const float* __restrict__ w, u16* __restrict__ wt,
                             int K, int N) {
  __shared__ float lt[64][65];
  const int e = blockIdx.z, k0 = blockIdx.y * 64, n0 = blockIdx.x * 64;
  const float* src = w + (size_t)e * K * N;
  u16* dst = wt + (size_t)e * N * K;
  const int t = threadIdx.x;
  const int tr = t >> 4, tc = (t & 15) * 4;
#pragma unroll
  for (int i = 0; i < 4; ++i) {
    f32x4 v = __builtin_nontemporal_load(
        (const f32x4*)(src + (size_t)(k0 + tr + i * 16) * N + n0 + tc));
    lt[tr + i * 16][tc] = v.x; lt[tr + i * 16][tc + 1] = v.y;
    lt[tr + i * 16][tc + 2] = v.z; lt[tr + i * 16][tc + 3] = v.w;
  }
  __syncthreads();
#pragma unroll
  for (int i = 0; i < 4; ++i) {
    int n = tr + i * 16;
    uint2 o;
    o.x = pack2(lt[tc + 0][n], lt[tc + 1][n]);
    o.y = pack2(lt[tc + 2][n], lt[tc + 3][n]);
    *(uint2*)(dst + (size_t)(n0 + n) * K + k0 + tc) = o;
  }
}

// ---------------- gating: 32 tokens/block, LDS-aggregated counts ----------------
__global__ void gate_kernel(const float* __restrict__ x, const float* __restrict__ wg,
                            int* __restrict__ cnt, int* __restrict__ tok_e,
                            float* __restrict__ tok_w) {
  __shared__ int lcnt[ENUM];
  const int tid = threadIdx.x;
  if (tid < ENUM) lcnt[tid] = 0;
  __syncthreads();
  const int wv = tid >> 6, lane = tid & 63;
  const int tbase = blockIdx.x * 32 + wv * 8;
  for (int t = 0; t < 8; ++t) {
    const int gw = tbase + t;
    const float* xr = x + (size_t)gw * CDIM;
    float acc[ENUM];
#pragma unroll
    for (int e = 0; e < ENUM; ++e) acc[e] = 0.f;
#pragma unroll 4
    for (int i = 0; i < CDIM / 64; ++i) {
      int c = i * 64 + lane;
      float xv = xr[c];
      float4 wa = *(const float4*)(wg + (size_t)c * ENUM);
      float4 wb = *(const float4*)(wg + (size_t)c * ENUM + 4);
      acc[0] += xv * wa.x; acc[1] += xv * wa.y; acc[2] += xv * wa.z; acc[3] += xv * wa.w;
      acc[4] += xv * wb.x; acc[5] += xv * wb.y; acc[6] += xv * wb.z; acc[7] += xv * wb.w;
    }
#pragma unroll
    for (int e = 0; e < ENUM; ++e) {
#pragma unroll
      for (int off = 32; off > 0; off >>= 1) acc[e] += __shfl_xor(acc[e], off);
    }
    if (lane == 0) {
      int i0 = 0; float v0 = acc[0];
#pragma unroll
      for (int e = 1; e < ENUM; ++e) if (acc[e] > v0) { v0 = acc[e]; i0 = e; }
      int i1 = -1; float v1 = -3.4e38f;
#pragma unroll
      for (int e = 0; e < ENUM; ++e) if (e != i0 && acc[e] > v1) { v1 = acc[e]; i1 = e; }
      float ex = expf(v1 - v0);
      float den = 1.f + ex;
      tok_e[gw * 2] = i0;     tok_w[gw * 2] = 1.f / den;
      tok_e[gw * 2 + 1] = i1; tok_w[gw * 2 + 1] = ex / den;
      atomicAdd(&lcnt[i0], 1); atomicAdd(&lcnt[i1], 1);
    }
  }
  __syncthreads();
  if (tid < ENUM) {
    int v = lcnt[tid];
    if (v) atomicAdd(&cnt[tid], v);
  }
}

__global__ void offsets_kernel(const int* __restrict__ cnt, int* __restrict__ offs) {
  if (threadIdx.x == 0 && blockIdx.x == 0) {
    int s = 0;
    for (int e = 0; e < ENUM; ++e) { offs[e] = s; s += cnt[e]; }
  }
}

// ---------------- assign: LDS-aggregated ranks, 8 global atomics/block ----------
__global__ void assign_kernel(const int* __restrict__ tok_e, const int* __restrict__ offs,
                              int* __restrict__ fill, int* __restrict__ slot_tok,
                              int* __restrict__ tok_slot) {
  __shared__ int lfill[ENUM], lbase[ENUM];
  const int tid = threadIdx.x;
  if (tid < ENUM) lfill[tid] = 0;
  __syncthreads();
  const int n = blockIdx.x * 256 + tid;
  const int e0 = tok_e[n * 2], e1 = tok_e[n * 2 + 1];
  const int p0 = atomicAdd(&lfill[e0], 1);
  const int p1 = atomicAdd(&lfill[e1], 1);
  __syncthreads();
  if (tid < ENUM) lbase[tid] = lfill[tid] ? atomicAdd(&fill[tid], lfill[tid]) : 0;
  __syncthreads();
  const int s0 = offs[e0] + lbase[e0] + p0;
  const int s1 = offs[e1] + lbase[e1] + p1;
  slot_tok[s0] = n; tok_slot[n * 2] = s0;
  slot_tok[s1] = n; tok_slot[n * 2 + 1] = s1;
}

__global__ void gather_kernel(const float* __restrict__ x, const int* __restrict__ slot_tok,
                              u16* __restrict__ xg) {
  int gid = blockIdx.x * blockDim.x + threadIdx.x;
  int slot = gid >> 8;
  int c4 = (gid & 255) * 4;
  int tok = slot_tok[slot];
  float4 v = *(const float4*)(x + (size_t)tok * CDIM + c4);
  uint2 o; o.x = pack2(v.x, v.y); o.y = pack2(v.z, v.w);
  *(uint2*)(xg + (size_t)slot * CDIM + c4) = o;
}

// ---------------- expert GEMMs (proven 128x128, BK=64, 4 waves, XCD-chunked) ----
// Session optimum: maximizes co-resident blocks (32 KB LDS, 64-VGPR class,
// ~2.3 blocks/CU) -> inter-block TLP hides the stage/barrier latency (m114).
// All deeper-pipeline / bigger-tile / persistent variants tested and falsified
// (R5, R7, R10, R12, R13, R14, R16).
template <int PHASE>
__global__ __launch_bounds__(256, 2) void moe_gemm(
    const u16* __restrict__ Ag, const u16* __restrict__ Bt, const float* __restrict__ bias,
    u16* __restrict__ outp,
    const int* __restrict__ cnts, const int* __restrict__ offs,
    int K, int Nn) {
  const int e = blockIdx.z;
  const int cnt = cnts[e];
  const int NT = gridDim.x;
  const int MTC = gridDim.y >> 3;               // 8
  const int r = blockIdx.y * NT + blockIdx.x;   // launch-order flat (x fastest)
  const int k = r & 7;                          // XCD id
  const int i = r >> 3;                         // inner
  const int ck = (k + e) & 7;                   // rotated chunk for balance
  const int mt = ck * MTC + (i % MTC);
  const int nt = i / MTC;
  if (mt * 128 >= cnt) return;
  const int moff = offs[e];
  const int tid = threadIdx.x;
  const int wv = tid >> 6, ln = tid & 63;
  const int lr = ln & 15, lg = ln >> 4;
  const int wm = wv >> 1, wn = wv & 1;

  __shared__ __align__(16) u16 lds[2][128 * 64];
  u16* lA = lds[0];
  u16* lB = lds[1];

  const u16* Abase = Ag + (size_t)moff * K;
  const u16* Bbase = Bt + (size_t)e * Nn * K + (size_t)nt * 128 * K;

  const int srow = ln >> 3;                       // row-in-chunk 0..7
  const int sk = (((ln & 7) ^ srow)) * 8;         // swizzled source octet offset

  f32x4 acc[4][4];
#pragma unroll
  for (int m = 0; m < 4; ++m)
#pragma unroll
    for (int n = 0; n < 4; ++n) {
      acc[m][n][0] = 0.f; acc[m][n][1] = 0.f; acc[m][n][2] = 0.f; acc[m][n][3] = 0.f;
    }

  const int nk = K / 64;
  for (int kt = 0; kt < nk; ++kt) {
#pragma unroll
    for (int i4 = 0; i4 < 4; ++i4) {
      int c = wv * 4 + i4;
      int ra = mt * 128 + c * 8 + srow;
      ra = ra < cnt ? ra : cnt - 1;  // clamp: padded rows discarded in epilogue
      gload16(Abase + (size_t)ra * K + kt * 64 + sk, lA + c * 512);
      gload16(Bbase + (size_t)(c * 8 + srow) * K + kt * 64 + sk, lB + c * 512);
    }
    __syncthreads();
#pragma unroll
    for (int ko = 0; ko < 2; ++ko) {
      s16x8 af[4], bfr[4];
      const int lsw = lr & 7;
#pragma unroll
      for (int m = 0; m < 4; ++m)
        af[m] = *(const s16x8*)(lA + (wm * 64 + m * 16 + lr) * 64 + ((ko * 4 + lg) ^ lsw) * 8);
#pragma unroll
      for (int n = 0; n < 4; ++n)
        bfr[n] = *(const s16x8*)(lB + (wn * 64 + n * 16 + lr) * 64 + ((ko * 4 + lg) ^ lsw) * 8);
#pragma unroll
      for (int m = 0; m < 4; ++m)
#pragma unroll
        for (int n = 0; n < 4; ++n)
          acc[m][n] = __builtin_amdgcn_mfma_f32_16x16x32_bf16(af[m], bfr[n], acc[m][n], 0, 0, 0);
    }
    __syncthreads();
  }

  // epilogue: bias (+gelu), pack bf16 into LDS tile [128][128], coalesced store
  u16* lT = lds[0];
  float bv[4];
#pragma unroll
  for (int n = 0; n < 4; ++n) bv[n] = bias[(size_t)e * Nn + nt * 128 + wn * 64 + n * 16 + lr];
#pragma unroll
  for (int m = 0; m < 4; ++m) {
#pragma unroll
    for (int r4 = 0; r4 < 4; ++r4) {
      int row = wm * 64 + m * 16 + lg * 4 + r4;
#pragma unroll
      for (int n = 0; n < 4; ++n) {
        int col = wn * 64 + n * 16 + lr;
        float v = acc[m][n][r4] + bv[n];
        if (PHASE == 1) v = gelu_fast(v);
        lT[row * 128 + col] = f2bf(v);
      }
    }
  }
  __syncthreads();
#pragma unroll
  for (int j = 0; j < 8; ++j) {
    int u = j * 256 + tid;           // u32x4 index into 128x128 tile
    int row = u >> 4;                // 16 u32x4 per row
    int colb = (u & 15) * 8;
    int grow = mt * 128 + row;
    if (grow < cnt) {
      u32x4 v = ((const u32x4*)lT)[u];
      *(u32x4*)(outp + (size_t)(moff + grow) * Nn + nt * 128 + colb) = v;
    }
  }
}

// out[tok] = w0 * y[slot0] + w1 * y[slot1]   (y read-once -> NT loads)
__global__ void combine_kernel(const u16* __restrict__ y, const int* __restrict__ tok_slot,
                               const float* __restrict__ tok_w, float* __restrict__ out) {
  int gid = blockIdx.x * blockDim.x + threadIdx.x;
  int n = gid >> 8;
  int c4 = (gid & 255) * 4;
  int s0 = tok_slot[n * 2], s1 = tok_slot[n * 2 + 1];
  float w0 = tok_w[n * 2], w1 = tok_w[n * 2 + 1];
  u32x2 a = __builtin_nontemporal_load((const u32x2*)(y + (size_t)s0 * CDIM + c4));
  u32x2 b = __builtin_nontemporal_load((const u32x2*)(y + (size_t)s1 * CDIM + c4));
  float4 o;
  o.x = w0 * bflo(a.x) + w1 * bflo(b.x);
  o.y = w0 * bfhi(a.x) + w1 * bfhi(b.x);
  o.z = w0 * bflo(a.y) + w1 * bflo(b.y);
  o.w = w0 * bfhi(a.y) + w1 * bfhi(b.y);
  *(float4*)(out + (size_t)n * CDIM + c4) = o;
}

extern "C" void kernel_launch(void* const* d_in, const int* in_sizes, int n_in,
                              void* d_out, int out_size, void* d_ws, size_t ws_size,
                              hipStream_t stream) {
  const float* x  = (const float*)d_in[0];
  const float* wg = (const float*)d_in[1];
  const float* w1 = (const float*)d_in[2];
  const float* b1 = (const float*)d_in[3];
  const float* w2 = (const float*)d_in[4];
  const float* b2 = (const float*)d_in[5];
  float* out = (float*)d_out;

  char* ws = (char*)d_ws;
  int* cnt  = (int*)ws;
  int* fill = cnt + 8;
  int* offs = cnt + 16;
  size_t off = 256;
  int*   tok_e    = (int*)(ws + off);   off += (size_t)NTOK * 2 * 4;
  float* tok_w    = (float*)(ws + off); off += (size_t)NTOK * 2 * 4;
  int*   slot_tok = (int*)(ws + off);   off += (size_t)NTOK * 2 * 4;
  int*   tok_slot = (int*)(ws + off);   off += (size_t)NTOK * 2 * 4;
  u16*   xg  = (u16*)(ws + off); off += (size_t)NTOK * 2 * CDIM * 2;
  u16*   h   = (u16*)(ws + off); off += (size_t)NTOK * 2 * HDIM * 2;
  u16*   y   = (u16*)(ws + off); off += (size_t)NTOK * 2 * CDIM * 2;
  u16*   w1t = (u16*)(ws + off); off += (size_t)ENUM * CDIM * HDIM * 2;
  u16*   w2t = (u16*)(ws + off); off += (size_t)ENUM * HDIM * CDIM * 2;

  hipMemsetAsync(cnt, 0, 64, stream);

  wconv_kernel<<<dim3(HDIM / 64, CDIM / 64, ENUM), 256, 0, stream>>>(w1, w1t, CDIM, HDIM);
  wconv_kernel<<<dim3(CDIM / 64, HDIM / 64, ENUM), 256, 0, stream>>>(w2, w2t, HDIM, CDIM);

  gate_kernel<<<NTOK / 32, 256, 0, stream>>>(x, wg, cnt, tok_e, tok_w);
  offsets_kernel<<<1, 64, 0, stream>>>(cnt, offs);
  assign_kernel<<<NTOK / 256, 256, 0, stream>>>(tok_e, offs, fill, slot_tok, tok_slot);
  gather_kernel<<<NTOK * 2, 256, 0, stream>>>(x, slot_tok, xg);

  moe_gemm<1><<<dim3(HDIM / 128, NTOK / 128, ENUM), 256, 0, stream>>>(
      xg, w1t, b1, h, cnt, offs, CDIM, HDIM);
  moe_gemm<2><<<dim3(CDIM / 128, NTOK / 128, ENUM), 256, 0, stream>>>(
      h, w2t, b2, y, cnt, offs, HDIM, CDIM);

  combine_kernel<<<NTOK, 256, 0, stream>>>(y, tok_slot, tok_w, out);
}